// Round 5
// baseline (450.938 us; speedup 1.0000x reference)
//
#include <hip/hip_runtime.h>

#define Bsz 8
#define Lx 4096
#define DM 64
#define DI 128
#define NS 16
#define RK 4
#define KC 4
#define NC 64
#define CT 64
#define SS 16
#define TRE 16

__device__ __forceinline__ float fsig(float x){ return 1.f/(1.f+__expf(-x)); }
__device__ __forceinline__ float dot4(float4 a, float4 b){
  return fmaf(a.x,b.x, fmaf(a.y,b.y, fmaf(a.z,b.z, a.w*b.w)));
}

// ---------------------------------------------------------------------------
// A1 v4: LN + in_proj (9x4 reg tile, 512 thr) + conv + silu + x_proj + dt
// launch_bounds(512,1): empirically arg2 = workgroups/CU -> VGPR cap 256.
// Live set ~160-190 -> no spill (rounds 2-4 were all scratch-bound).
// ---------------------------------------------------------------------------
__global__ __launch_bounds__(512, 1) void a1_front(
    const float* __restrict__ x, const float* __restrict__ ln_g, const float* __restrict__ ln_b,
    const float* __restrict__ in_w, const float* __restrict__ conv_w, const float* __restrict__ conv_b,
    const float* __restrict__ xp_w, const float* __restrict__ dtp_w, const float* __restrict__ dt_b,
    float* __restrict__ xcg, float* __restrict__ dtg, float* __restrict__ zg,
    float* __restrict__ Bg, float* __restrict__ Cg)
{
  __shared__ float uA[8704];
  __shared__ float uB[8704];
  const int tid = threadIdx.x;
  const int bx = blockIdx.x;
  const int tile = bx & 63;
  const int i = (bx >> 6) & 1;
  const int b = bx >> 7;
  const int l0 = tile * 64;
  const size_t rbase = (size_t)(b*2+i)*Lx + l0;

  // ---- phase 1: layernorm rows l0-3 .. l0+63 into swizzled s_x ----
  {
    const int wv = tid >> 6, lane = tid & 63;
    const float gg = ln_g[lane], bb = ln_b[lane];
    for (int lr = wv; lr < 67; lr += 8) {
      int l = l0 - 3 + lr;
      float v = 0.f;
      if (l >= 0) {
        int pl = i ? (Lx-1-l) : l;
        v = x[((size_t)b*Lx + pl)*DM + lane];
        float s = v, s2 = v*v;
        #pragma unroll
        for (int off=32; off; off>>=1){ s += __shfl_xor(s,off); s2 += __shfl_xor(s2,off); }
        float mu = s * (1.f/DM);
        float rs = rsqrtf(s2*(1.f/DM) - mu*mu + 1e-5f);
        v = (v-mu)*rs*gg + bb;
      }
      uA[lr*64 + 4*((lane>>2) ^ (lr&7)) + (lane&3)] = v;
    }
  }

  // ---- phase 2: in_proj GEMM, per-thread 9 rows x 4 channels ----
  const int rg = tid & 7;        // 8 row-groups of 9 rows
  const int cg = tid >> 3;       // 64 channel-groups of 4 channels
  float acc[9][4];
  #pragma unroll
  for (int j=0;j<9;++j)
    #pragma unroll
    for (int jc=0;jc<4;++jc) acc[j][jc] = 0.f;

  for (int half = 0; half < 2; ++half) {
    __syncthreads();
    #pragma unroll
    for (int it=0; it<4; ++it) {           // stage 256ch x 8 quads
      int g = it*512 + tid;
      int c = g >> 3, q = g & 7;
      float4 w = *(const float4*)(in_w + ((size_t)(i*2*DI) + c)*DM + half*32 + q*4);
      *(float4*)&uB[c*32 + 4*(q ^ ((c>>2)&7))] = w;
    }
    __syncthreads();
    #pragma unroll
    for (int q=0; q<8; ++q) {
      float4 wq[4];
      #pragma unroll
      for (int jc=0;jc<4;++jc)
        wq[jc] = *(const float4*)&uB[(cg*4+jc)*32 + 4*(q ^ (cg&7))];
      #pragma unroll
      for (int j=0;j<9;++j) {
        int r = rg*9 + j;
        float4 xq = *(const float4*)&uA[r*64 + 4*((half*8+q) ^ (r&7))];
        #pragma unroll
        for (int jc=0;jc<4;++jc)
          acc[j][jc] += dot4(xq, wq[jc]);
      }
    }
  }
  __syncthreads();

  // ---- phase 3: xi -> uB (swizzled), z -> uA [64][132] ----
  if (cg < 32) {
    #pragma unroll
    for (int j=0;j<9;++j) {
      int lr = rg*9 + j;
      if (lr <= 66) {
        float4 v = make_float4(acc[j][0],acc[j][1],acc[j][2],acc[j][3]);
        *(float4*)&uB[lr*128 + 4*(cg ^ (lr&7))] = v;
      }
    }
  } else {
    #pragma unroll
    for (int j=0;j<9;++j) {
      int lr = rg*9 + j;
      if (lr >= 3 && lr <= 66) {
        float4 v = make_float4(acc[j][0],acc[j][1],acc[j][2],acc[j][3]);
        *(float4*)&uA[(lr-3)*132 + (cg-32)*4] = v;
      }
    }
  }
  __syncthreads();

  // ---- phase 3b: z -> global, coalesced ----
  #pragma unroll
  for (int it=0; it<4; ++it) {
    int f = it*512 + tid;
    int row = f >> 5, c0 = (f & 31) * 4;
    float4 v = *(const float4*)&uA[row*132 + c0];
    *(float4*)&zg[(rbase + row)*DI + c0] = v;
  }
  __syncthreads();

  // ---- phase 4: causal conv + silu -> s_xc (uA) + xcg ----
  {
    const int d = tid & 127, rh = tid >> 7;
    float4 cw = *(const float4*)(conv_w + (size_t)(i*DI + d)*KC);
    const float cb = conv_b[i*DI + d];
    const int qd = d >> 2, de = d & 3;
    #pragma unroll 4
    for (int rr=0; rr<16; ++rr) {
      int lr = 3 + rh*16 + rr;
      float v0 = uB[(lr-3)*128 + 4*(qd ^ ((lr-3)&7)) + de];
      float v1 = uB[(lr-2)*128 + 4*(qd ^ ((lr-2)&7)) + de];
      float v2 = uB[(lr-1)*128 + 4*(qd ^ ((lr-1)&7)) + de];
      float v3 = uB[(lr  )*128 + 4*(qd ^ ((lr  )&7)) + de];
      float a = cb + cw.x*v0 + cw.y*v1 + cw.z*v2 + cw.w*v3;
      float xc = a * fsig(a);
      int r = lr - 3;
      uA[r*132 + d] = xc;
      xcg[(rbase + r)*DI + d] = xc;
    }
  }
  __syncthreads();

  // ---- phase 5: stage xp_w into uB (s_xi dead) ----
  for (int e = tid; e < 36*32; e += 512) {
    int j = e >> 5, q = e & 31;
    *(float4*)&uB[j*132 + 4*q] = *(const float4*)(xp_w + ((size_t)(i*36) + j)*DI + q*4);
  }
  __syncthreads();

  // ---- phase 6: x_proj, thread = (2 rows) x (3 outs strided by 16) ----
  {
    const int rg2 = tid & 31, jg = tid >> 5;
    const int j2 = (jg < 4) ? (jg + 32) : 35;
    float a2[2][3];
    #pragma unroll
    for (int rc=0;rc<2;++rc)
      #pragma unroll
      for (int jc=0;jc<3;++jc) a2[rc][jc]=0.f;
    #pragma unroll 4
    for (int q=0; q<32; ++q) {
      float4 x0 = *(const float4*)&uA[(rg2*2  )*132 + 4*q];
      float4 x1 = *(const float4*)&uA[(rg2*2+1)*132 + 4*q];
      float4 w0 = *(const float4*)&uB[jg*132 + 4*q];
      float4 w1 = *(const float4*)&uB[(jg+16)*132 + 4*q];
      float4 w2 = *(const float4*)&uB[j2*132 + 4*q];
      a2[0][0] += dot4(x0,w0); a2[0][1] += dot4(x0,w1); a2[0][2] += dot4(x0,w2);
      a2[1][0] += dot4(x1,w0); a2[1][1] += dot4(x1,w1); a2[1][2] += dot4(x1,w2);
    }
    #pragma unroll
    for (int rc=0;rc<2;++rc) {
      int r = rg2*2 + rc;
      if (jg < 4) uA[8448 + r*4 + jg] = a2[rc][0];
      else        uB[4864 + r*32 + (jg-4)] = a2[rc][0];
      uB[4864 + r*32 + (jg+12)] = a2[rc][1];
      if (jg < 4) uB[4864 + r*32 + (jg+28)] = a2[rc][2];
    }
  }
  __syncthreads();

  // ---- phase 6b: B/C -> global coalesced ----
  #pragma unroll
  for (int it=0; it<2; ++it) {
    int e = it*512 + tid;
    int r = e >> 4, n = e & 15;
    Bg[(rbase + r)*NS + n] = uB[4864 + r*32 + n];
    Cg[(rbase + r)*NS + n] = uB[4864 + r*32 + 16 + n];
  }

  // ---- phase 7: dt = softplus(dtl @ dtp_w^T + bias) ----
  #pragma unroll 4
  for (int it=0; it<16; ++it) {
    int e = it*512 + tid;
    int r = e >> 7, d = e & 127;
    float4 dl = *(const float4*)&uA[8448 + r*4];
    float4 w  = *(const float4*)(dtp_w + (size_t)(i*DI + d)*RK);
    float a = dt_b[i*DI + d] + dot4(w, dl);
    dtg[(rbase + r)*DI + d] = (a > 20.f) ? a : log1pf(__expf(a));
  }
}

// ---------------------------------------------------------------------------
// KB: pass1 — per-chunk local scan (h0=0) + P = exp(A*sum(dt))
// ---------------------------------------------------------------------------
__global__ __launch_bounds__(256) void kb_pass1(
    const float* __restrict__ dtg, const float* __restrict__ xcg, const float* __restrict__ Bg,
    const float* __restrict__ A_log,
    float* __restrict__ Pm, float* __restrict__ hend)
{
  __shared__ float s_dt[SS][DI];
  __shared__ float s_x[SS][DI];
  __shared__ float s_B[SS][NS];
  const int tid = threadIdx.x;
  const int bx = blockIdx.x;
  const int c = bx % NC; const int i = (bx/NC)&1; const int b = bx/(2*NC);
  const int d = tid >> 1, half = tid & 1, n0 = half*8;
  float a[8], h[8];
  bool afast = true;
  #pragma unroll
  for (int n=0;n<8;++n){
    a[n] = -__expf(A_log[((size_t)(i*DI)+d)*NS + n0+n]);
    float tgt = (float)(n0+n+1);
    afast = afast && (fabsf(a[n] + tgt) <= 1e-4f*tgt);
    h[n] = 0.f;
  }
  float S = 0.f;
  const size_t rb = ((size_t)(b*2+i)*Lx + (size_t)c*CT);
  for (int s=0; s<CT/SS; ++s){
    __syncthreads();
    #pragma unroll
    for (int it=0, e=tid; it<(SS*DI)/256; ++it, e+=256){
      int t = e >> 7, dd = e & (DI-1);
      size_t g = (rb + s*SS + t)*DI + dd;
      s_dt[t][dd] = dtg[g];
      s_x[t][dd]  = xcg[g];
    }
    {
      int t = tid >> 4, nn = tid & (NS-1);
      s_B[t][nn] = Bg[(rb + s*SS + t)*NS + nn];
    }
    __syncthreads();
    #pragma unroll
    for (int t=0;t<SS;++t){
      float dtt = s_dt[t][d];
      float u = dtt * s_x[t][d];
      S += dtt;
      float4 b0 = *(const float4*)(&s_B[t][n0]);
      float4 b1 = *(const float4*)(&s_B[t][n0+4]);
      float bb[8] = {b0.x,b0.y,b0.z,b0.w,b1.x,b1.y,b1.z,b1.w};
      if (afast){
        float rr = __expf(-dtt);
        float dA;
        if (half){ float r2=rr*rr, r4=r2*r2; dA = r4*r4*rr; } else dA = rr;
        h[0] = fmaf(dA, h[0], u*bb[0]);
        #pragma unroll
        for (int n=1;n<8;++n){ dA *= rr; h[n] = fmaf(dA, h[n], u*bb[n]); }
      } else {
        #pragma unroll
        for (int n=0;n<8;++n){
          float dA = __expf(a[n]*dtt);
          h[n] = fmaf(dA, h[n], u*bb[n]);
        }
      }
    }
  }
  size_t ob = (((size_t)(b*2+i)*NC + c)*DI + d)*NS + n0;
  #pragma unroll
  for (int n=0;n<8;++n){
    Pm[ob+n] = __expf(a[n]*S);
    hend[ob+n] = h[n];
  }
}

// ---------------------------------------------------------------------------
// KC: pass2 — propagate chunk boundary states; h0 written IN PLACE over Pm
// ---------------------------------------------------------------------------
__global__ __launch_bounds__(256) void kc_pass2(
    float* __restrict__ Pm, const float* __restrict__ hend)
{
  const int tid = threadIdx.x;
  const int bi = blockIdx.x;
  const int d = tid>>1, n0 = (tid&1)*8;
  float h[8];
  #pragma unroll
  for (int n=0;n<8;++n) h[n]=0.f;
  for (int c=0;c<NC;++c){
    size_t ob = (((size_t)bi*NC + c)*DI + d)*NS + n0;
    float p[8], he[8];
    #pragma unroll
    for (int n=0;n<8;++n){ p[n]=Pm[ob+n]; he[n]=hend[ob+n]; }
    #pragma unroll
    for (int n=0;n<8;++n){ Pm[ob+n] = h[n]; h[n] = fmaf(p[n], h[n], he[n]); }
  }
}

// ---------------------------------------------------------------------------
// KD: pass3 — scan with true h0, y = C.h + D-skip, gate silu(z); y -> dtg
// ---------------------------------------------------------------------------
__global__ __launch_bounds__(256) void kd_pass3(
    const float* dtg, const float* __restrict__ xcg, const float* __restrict__ Bg,
    const float* __restrict__ Cg, const float* __restrict__ A_log, const float* __restrict__ Dp,
    const float* __restrict__ h0, const float* __restrict__ zg, float* yout)
{
  __shared__ float s_dt[SS][DI];
  __shared__ float s_x[SS][DI];
  __shared__ float s_z[SS][DI];
  __shared__ float s_B[SS][NS];
  __shared__ float s_C[SS][NS];
  const int tid = threadIdx.x;
  const int bx = blockIdx.x;
  const int c = bx % NC; const int i = (bx/NC)&1; const int b = bx/(2*NC);
  const int d = tid >> 1, half = tid & 1, n0 = half*8;
  float a[8], h[8];
  bool afast = true;
  size_t hb = (((size_t)(b*2+i)*NC + c)*DI + d)*NS + n0;
  #pragma unroll
  for (int n=0;n<8;++n){
    a[n] = -__expf(A_log[((size_t)(i*DI)+d)*NS + n0+n]);
    float tgt = (float)(n0+n+1);
    afast = afast && (fabsf(a[n] + tgt) <= 1e-4f*tgt);
    h[n] = h0[hb+n];
  }
  const float Dd = Dp[i*DI + d];
  const size_t rb = ((size_t)(b*2+i)*Lx + (size_t)c*CT);
  for (int s=0; s<CT/SS; ++s){
    __syncthreads();
    #pragma unroll
    for (int it=0, e=tid; it<(SS*DI)/256; ++it, e+=256){
      int t = e >> 7, dd = e & (DI-1);
      size_t g = (rb + s*SS + t)*DI + dd;
      s_dt[t][dd] = dtg[g];
      s_x[t][dd]  = xcg[g];
      s_z[t][dd]  = zg[g];
    }
    {
      int t = tid >> 4, nn = tid & (NS-1);
      s_B[t][nn] = Bg[(rb + s*SS + t)*NS + nn];
      s_C[t][nn] = Cg[(rb + s*SS + t)*NS + nn];
    }
    __syncthreads();
    #pragma unroll
    for (int t=0;t<SS;++t){
      float dtt = s_dt[t][d];
      float xcv = s_x[t][d];
      float u = dtt * xcv;
      float4 b0 = *(const float4*)(&s_B[t][n0]);
      float4 b1 = *(const float4*)(&s_B[t][n0+4]);
      float4 c0 = *(const float4*)(&s_C[t][n0]);
      float4 c1 = *(const float4*)(&s_C[t][n0+4]);
      float bb[8] = {b0.x,b0.y,b0.z,b0.w,b1.x,b1.y,b1.z,b1.w};
      float cc[8] = {c0.x,c0.y,c0.z,c0.w,c1.x,c1.y,c1.z,c1.w};
      float part = 0.f;
      if (afast){
        float rr = __expf(-dtt);
        float dA;
        if (half){ float r2=rr*rr, r4=r2*r2; dA = r4*r4*rr; } else dA = rr;
        h[0] = fmaf(dA, h[0], u*bb[0]);
        part = fmaf(h[0], cc[0], part);
        #pragma unroll
        for (int n=1;n<8;++n){
          dA *= rr;
          h[n] = fmaf(dA, h[n], u*bb[n]);
          part = fmaf(h[n], cc[n], part);
        }
      } else {
        #pragma unroll
        for (int n=0;n<8;++n){
          float dA = __expf(a[n]*dtt);
          h[n] = fmaf(dA, h[n], u*bb[n]);
          part = fmaf(h[n], cc[n], part);
        }
      }
      float y = part + __shfl_xor(part, 1);
      if (half == 0){
        float zz = s_z[t][d];
        yout[(rb + s*SS + t)*DI + d] = fmaf(xcv, Dd, y) * (zz * fsig(zz));
      }
    }
  }
}

// ---------------------------------------------------------------------------
// KE: out-proj, sum both directions (dir1 read flipped)
// ---------------------------------------------------------------------------
__global__ __launch_bounds__(256) void ke_out(
    const float* __restrict__ yg, const float* __restrict__ ow, float* __restrict__ out)
{
  __shared__ float s_y0[TRE][DI];
  __shared__ float s_y1[TRE][DI];
  const int tid = threadIdx.x;
  const int bx = blockIdx.x;
  const int ntile = Lx / TRE;
  const int tile = bx % ntile; const int b = bx / ntile;
  const int l0 = tile * TRE;
  #pragma unroll
  for (int it=0, e=tid; it<(TRE*DI)/256; ++it, e+=256){
    int r = e >> 7, dd = e & (DI-1);
    s_y0[r][dd] = yg[((size_t)(b*2+0)*Lx + (size_t)(l0+r))*DI + dd];
    s_y1[r][dd] = yg[((size_t)(b*2+1)*Lx + (size_t)(Lx-1-(l0+r)))*DI + dd];
  }
  __syncthreads();
  const int m = tid & 63, r0 = tid >> 6;
  const float4* w0 = (const float4*)(ow + (size_t)m*DI);
  const float4* w1 = (const float4*)(ow + (size_t)(DM+m)*DI);
  float acc[4] = {0.f,0.f,0.f,0.f};
  #pragma unroll
  for (int k=0;k<DI/4;++k){
    float4 a0 = w0[k], a1 = w1[k];
    #pragma unroll
    for (int j=0;j<4;++j){
      const float4 y0 = *(const float4*)(&s_y0[r0+j*4][k*4]);
      const float4 y1 = *(const float4*)(&s_y1[r0+j*4][k*4]);
      acc[j] += dot4(a0,y0) + dot4(a1,y1);
    }
  }
  #pragma unroll
  for (int j=0;j<4;++j)
    out[((size_t)b*Lx + (size_t)(l0 + r0 + j*4))*DM + m] = acc[j];
}

extern "C" void kernel_launch(void* const* d_in, const int* in_sizes, int n_in,
                              void* d_out, int out_size, void* d_ws, size_t ws_size,
                              hipStream_t stream)
{
  const float* x      = (const float*)d_in[0];
  const float* ln_g   = (const float*)d_in[1];
  const float* ln_b   = (const float*)d_in[2];
  const float* in_w   = (const float*)d_in[3];
  const float* conv_w = (const float*)d_in[4];
  const float* conv_b = (const float*)d_in[5];
  const float* xp_w   = (const float*)d_in[6];
  const float* dtp_w  = (const float*)d_in[7];
  const float* dt_b   = (const float*)d_in[8];
  const float* A_log  = (const float*)d_in[9];
  const float* Dp     = (const float*)d_in[10];
  const float* ow     = (const float*)d_in[11];
  float* out = (float*)d_out;
  float* ws = (float*)d_ws;
  const size_t NBD = (size_t)Bsz*2*Lx*DI;     // 8,388,608
  const size_t NBN = (size_t)Bsz*2*Lx*NS;     // 1,048,576
  float* xcg = ws;
  float* dtg = xcg + NBD;
  float* zg  = dtg + NBD;
  float* Bg  = zg + NBD;
  float* Cg  = Bg + NBN;
  float* Pm  = Cg + NBN;          // Bsz*2*NC*DI*NS = 2,097,152 floats; becomes h0 after kc
  float* he  = out;               // hend staged in d_out (fully overwritten by ke)

  a1_front<<<dim3(Bsz*2*(Lx/64)), dim3(512), 0, stream>>>(
      x, ln_g, ln_b, in_w, conv_w, conv_b, xp_w, dtp_w, dt_b, xcg, dtg, zg, Bg, Cg);
  kb_pass1<<<dim3(Bsz*2*NC), dim3(256), 0, stream>>>(dtg, xcg, Bg, A_log, Pm, he);
  kc_pass2<<<dim3(Bsz*2), dim3(256), 0, stream>>>(Pm, he);
  kd_pass3<<<dim3(Bsz*2*NC), dim3(256), 0, stream>>>(dtg, xcg, Bg, Cg, A_log, Dp, Pm, zg, dtg);
  ke_out<<<dim3(Bsz*(Lx/TRE)), dim3(256), 0, stream>>>(dtg, ow, out);
}

// Round 6
// 271.748 us; speedup vs baseline: 1.6594x; 1.6594x over previous
//
#include <hip/hip_runtime.h>

#define Bsz 8
#define Lx 4096
#define DM 64
#define DI 128
#define NS 16
#define RK 4
#define KC 4
#define NC 64
#define CT 64
#define SS 16
#define TRE 16

__device__ __forceinline__ float fsig(float x){ return 1.f/(1.f+__expf(-x)); }
__device__ __forceinline__ float dot4(float4 a, float4 b){
  return fmaf(a.x,b.x, fmaf(a.y,b.y, fmaf(a.z,b.z, a.w*b.w)));
}

// ---------------------------------------------------------------------------
// A1 v5: LN + in_proj (two channel-half passes, 9x2 acc each) + conv + x_proj + dt
// Live set ~90-100 VGPR -> fits the allocator's 128 cap with NO spill
// (rounds 2-5 all scratch-bound; cap can't be raised, so shrink the tile).
// uA[8704]: s_x[67][64] swz -> z/s_xc[64][132] + dtl@8448
// uB[8704]: w-pass[128][64] swz -> s_xi[67][129] -> xp_w[36][132] + s_BC@4864
// ---------------------------------------------------------------------------
__global__ __launch_bounds__(512) void a1_front(
    const float* __restrict__ x, const float* __restrict__ ln_g, const float* __restrict__ ln_b,
    const float* __restrict__ in_w, const float* __restrict__ conv_w, const float* __restrict__ conv_b,
    const float* __restrict__ xp_w, const float* __restrict__ dtp_w, const float* __restrict__ dt_b,
    float* __restrict__ xcg, float* __restrict__ dtg, float* __restrict__ zg,
    float* __restrict__ Bg, float* __restrict__ Cg)
{
  __shared__ float uA[8704];
  __shared__ float uB[8704];
  const int tid = threadIdx.x;
  const int bx = blockIdx.x;
  const int tile = bx & 63;
  const int i = (bx >> 6) & 1;
  const int b = bx >> 7;
  const int l0 = tile * 64;
  const size_t rbase = (size_t)(b*2+i)*Lx + l0;

  // ---- phase 1: layernorm rows l0-3 .. l0+63 into swizzled s_x ----
  {
    const int wv = tid >> 6, lane = tid & 63;
    const float gg = ln_g[lane], bb = ln_b[lane];
    for (int lr = wv; lr < 67; lr += 8) {
      int l = l0 - 3 + lr;
      float v = 0.f;
      if (l >= 0) {
        int pl = i ? (Lx-1-l) : l;
        v = x[((size_t)b*Lx + pl)*DM + lane];
        float s = v, s2 = v*v;
        #pragma unroll
        for (int off=32; off; off>>=1){ s += __shfl_xor(s,off); s2 += __shfl_xor(s2,off); }
        float mu = s * (1.f/DM);
        float rs = rsqrtf(s2*(1.f/DM) - mu*mu + 1e-5f);
        v = (v-mu)*rs*gg + bb;
      }
      uA[lr*64 + 4*((lane>>2) ^ (lr&7)) + (lane&3)] = v;
    }
  }

  // ---- phase 2: in_proj GEMM, two channel-half passes, 9 rows x 2 ch each ----
  const int rg = tid & 7;        // 8 row-groups of 9 rows
  const int cg = tid >> 3;       // 64 groups of 2 channels within the half
  float axi[9][2], az[9][2];
  #pragma unroll
  for (int j=0;j<9;++j){ axi[j][0]=axi[j][1]=az[j][0]=az[j][1]=0.f; }

  #pragma unroll
  for (int p = 0; p < 2; ++p) {
    __syncthreads();               // uA ready (p=0) / uB reads done (p=1)
    #pragma unroll
    for (int it=0; it<4; ++it) {   // stage 128 ch x 16 quads (full K)
      int g = it*512 + tid;
      int c = g >> 4, q = g & 15;
      float4 w = *(const float4*)(in_w + ((size_t)(i*2*DI) + p*DI + c)*DM + q*4);
      *(float4*)&uB[c*64 + 4*(q ^ ((c>>1)&7))] = w;
    }
    __syncthreads();
    #pragma unroll 4
    for (int q=0; q<16; ++q) {
      float4 w0 = *(const float4*)&uB[(cg*2  )*64 + 4*(q ^ (cg&7))];
      float4 w1 = *(const float4*)&uB[(cg*2+1)*64 + 4*(q ^ (cg&7))];
      #pragma unroll
      for (int j=0;j<9;++j) {
        int r = rg*9 + j;
        float4 xq = *(const float4*)&uA[r*64 + 4*(q ^ (r&7))];
        if (p == 0) { axi[j][0] += dot4(xq, w0); axi[j][1] += dot4(xq, w1); }
        else        { az[j][0]  += dot4(xq, w0); az[j][1]  += dot4(xq, w1); }
      }
    }
  }
  __syncthreads();

  // ---- phase 3: xi -> uB[67][129], z -> uA[64][132] ----
  #pragma unroll
  for (int j=0;j<9;++j) {
    int lr = rg*9 + j;
    if (lr <= 66) {
      uB[lr*129 + cg*2    ] = axi[j][0];
      uB[lr*129 + cg*2 + 1] = axi[j][1];
      int r = lr - 3;
      if (r >= 0) *(float2*)&uA[r*132 + cg*2] = make_float2(az[j][0], az[j][1]);
    }
  }
  __syncthreads();

  // ---- phase 3b: z -> global, coalesced ----
  #pragma unroll
  for (int it=0; it<4; ++it) {
    int f = it*512 + tid;
    int row = f >> 5, c0 = (f & 31) * 4;
    float4 v = *(const float4*)&uA[row*132 + c0];
    *(float4*)&zg[(rbase + row)*DI + c0] = v;
  }
  __syncthreads();

  // ---- phase 4: causal conv + silu -> s_xc (uA) + xcg ----
  {
    const int d = tid & 127, rh = tid >> 7;
    float4 cw = *(const float4*)(conv_w + (size_t)(i*DI + d)*KC);
    const float cb = conv_b[i*DI + d];
    #pragma unroll 4
    for (int rr=0; rr<16; ++rr) {
      int lr = 3 + rh*16 + rr;
      float v0 = uB[(lr-3)*129 + d];
      float v1 = uB[(lr-2)*129 + d];
      float v2 = uB[(lr-1)*129 + d];
      float v3 = uB[(lr  )*129 + d];
      float a = cb + cw.x*v0 + cw.y*v1 + cw.z*v2 + cw.w*v3;
      float xc = a * fsig(a);
      int r = lr - 3;
      uA[r*132 + d] = xc;
      xcg[(rbase + r)*DI + d] = xc;
    }
  }
  __syncthreads();

  // ---- phase 5: stage xp_w into uB (s_xi dead) ----
  for (int e = tid; e < 36*32; e += 512) {
    int j = e >> 5, q = e & 31;
    *(float4*)&uB[j*132 + 4*q] = *(const float4*)(xp_w + ((size_t)(i*36) + j)*DI + q*4);
  }
  __syncthreads();

  // ---- phase 6: x_proj, thread = (2 rows) x (3 outs strided by 16) ----
  {
    const int rg2 = tid & 31, jg = tid >> 5;
    const int j2 = (jg < 4) ? (jg + 32) : 35;
    float a2[2][3];
    #pragma unroll
    for (int rc=0;rc<2;++rc)
      #pragma unroll
      for (int jc=0;jc<3;++jc) a2[rc][jc]=0.f;
    #pragma unroll 4
    for (int q=0; q<32; ++q) {
      float4 x0 = *(const float4*)&uA[(rg2*2  )*132 + 4*q];
      float4 x1 = *(const float4*)&uA[(rg2*2+1)*132 + 4*q];
      float4 w0 = *(const float4*)&uB[jg*132 + 4*q];
      float4 w1 = *(const float4*)&uB[(jg+16)*132 + 4*q];
      float4 w2 = *(const float4*)&uB[j2*132 + 4*q];
      a2[0][0] += dot4(x0,w0); a2[0][1] += dot4(x0,w1); a2[0][2] += dot4(x0,w2);
      a2[1][0] += dot4(x1,w0); a2[1][1] += dot4(x1,w1); a2[1][2] += dot4(x1,w2);
    }
    #pragma unroll
    for (int rc=0;rc<2;++rc) {
      int r = rg2*2 + rc;
      if (jg < 4) uA[8448 + r*4 + jg] = a2[rc][0];
      else        uB[4864 + r*32 + (jg-4)] = a2[rc][0];
      uB[4864 + r*32 + (jg+12)] = a2[rc][1];
      if (jg < 4) uB[4864 + r*32 + (jg+28)] = a2[rc][2];
    }
  }
  __syncthreads();

  // ---- phase 6b: B/C -> global coalesced ----
  #pragma unroll
  for (int it=0; it<2; ++it) {
    int e = it*512 + tid;
    int r = e >> 4, n = e & 15;
    Bg[(rbase + r)*NS + n] = uB[4864 + r*32 + n];
    Cg[(rbase + r)*NS + n] = uB[4864 + r*32 + 16 + n];
  }

  // ---- phase 7: dt = softplus(dtl @ dtp_w^T + bias) ----
  #pragma unroll 4
  for (int it=0; it<16; ++it) {
    int e = it*512 + tid;
    int r = e >> 7, d = e & 127;
    float4 dl = *(const float4*)&uA[8448 + r*4];
    float4 w  = *(const float4*)(dtp_w + (size_t)(i*DI + d)*RK);
    float a = dt_b[i*DI + d] + dot4(w, dl);
    dtg[(rbase + r)*DI + d] = (a > 20.f) ? a : log1pf(__expf(a));
  }
}

// ---------------------------------------------------------------------------
// KB: pass1 — per-chunk local scan (h0=0) + P = exp(A*sum(dt))
// ---------------------------------------------------------------------------
__global__ __launch_bounds__(256) void kb_pass1(
    const float* __restrict__ dtg, const float* __restrict__ xcg, const float* __restrict__ Bg,
    const float* __restrict__ A_log,
    float* __restrict__ Pm, float* __restrict__ hend)
{
  __shared__ float s_dt[SS][DI];
  __shared__ float s_x[SS][DI];
  __shared__ float s_B[SS][NS];
  const int tid = threadIdx.x;
  const int bx = blockIdx.x;
  const int c = bx % NC; const int i = (bx/NC)&1; const int b = bx/(2*NC);
  const int d = tid >> 1, half = tid & 1, n0 = half*8;
  float a[8], h[8];
  bool afast = true;
  #pragma unroll
  for (int n=0;n<8;++n){
    a[n] = -__expf(A_log[((size_t)(i*DI)+d)*NS + n0+n]);
    float tgt = (float)(n0+n+1);
    afast = afast && (fabsf(a[n] + tgt) <= 1e-4f*tgt);
    h[n] = 0.f;
  }
  float S = 0.f;
  const size_t rb = ((size_t)(b*2+i)*Lx + (size_t)c*CT);
  for (int s=0; s<CT/SS; ++s){
    __syncthreads();
    #pragma unroll
    for (int it=0, e=tid; it<(SS*DI)/256; ++it, e+=256){
      int t = e >> 7, dd = e & (DI-1);
      size_t g = (rb + s*SS + t)*DI + dd;
      s_dt[t][dd] = dtg[g];
      s_x[t][dd]  = xcg[g];
    }
    {
      int t = tid >> 4, nn = tid & (NS-1);
      s_B[t][nn] = Bg[(rb + s*SS + t)*NS + nn];
    }
    __syncthreads();
    #pragma unroll
    for (int t=0;t<SS;++t){
      float dtt = s_dt[t][d];
      float u = dtt * s_x[t][d];
      S += dtt;
      float4 b0 = *(const float4*)(&s_B[t][n0]);
      float4 b1 = *(const float4*)(&s_B[t][n0+4]);
      float bb[8] = {b0.x,b0.y,b0.z,b0.w,b1.x,b1.y,b1.z,b1.w};
      if (afast){
        float rr = __expf(-dtt);
        float dA;
        if (half){ float r2=rr*rr, r4=r2*r2; dA = r4*r4*rr; } else dA = rr;
        h[0] = fmaf(dA, h[0], u*bb[0]);
        #pragma unroll
        for (int n=1;n<8;++n){ dA *= rr; h[n] = fmaf(dA, h[n], u*bb[n]); }
      } else {
        #pragma unroll
        for (int n=0;n<8;++n){
          float dA = __expf(a[n]*dtt);
          h[n] = fmaf(dA, h[n], u*bb[n]);
        }
      }
    }
  }
  size_t ob = (((size_t)(b*2+i)*NC + c)*DI + d)*NS + n0;
  #pragma unroll
  for (int n=0;n<8;++n){
    Pm[ob+n] = __expf(a[n]*S);
    hend[ob+n] = h[n];
  }
}

// ---------------------------------------------------------------------------
// KC: pass2 — propagate chunk boundary states; h0 written IN PLACE over Pm
// ---------------------------------------------------------------------------
__global__ __launch_bounds__(256) void kc_pass2(
    float* __restrict__ Pm, const float* __restrict__ hend)
{
  const int tid = threadIdx.x;
  const int bi = blockIdx.x;
  const int d = tid>>1, n0 = (tid&1)*8;
  float h[8];
  #pragma unroll
  for (int n=0;n<8;++n) h[n]=0.f;
  for (int c=0;c<NC;++c){
    size_t ob = (((size_t)bi*NC + c)*DI + d)*NS + n0;
    float p[8], he[8];
    #pragma unroll
    for (int n=0;n<8;++n){ p[n]=Pm[ob+n]; he[n]=hend[ob+n]; }
    #pragma unroll
    for (int n=0;n<8;++n){ Pm[ob+n] = h[n]; h[n] = fmaf(p[n], h[n], he[n]); }
  }
}

// ---------------------------------------------------------------------------
// KD: pass3 — scan with true h0, y = C.h + D-skip, gate silu(z); y -> dtg
// ---------------------------------------------------------------------------
__global__ __launch_bounds__(256) void kd_pass3(
    const float* dtg, const float* __restrict__ xcg, const float* __restrict__ Bg,
    const float* __restrict__ Cg, const float* __restrict__ A_log, const float* __restrict__ Dp,
    const float* __restrict__ h0, const float* __restrict__ zg, float* yout)
{
  __shared__ float s_dt[SS][DI];
  __shared__ float s_x[SS][DI];
  __shared__ float s_z[SS][DI];
  __shared__ float s_B[SS][NS];
  __shared__ float s_C[SS][NS];
  const int tid = threadIdx.x;
  const int bx = blockIdx.x;
  const int c = bx % NC; const int i = (bx/NC)&1; const int b = bx/(2*NC);
  const int d = tid >> 1, half = tid & 1, n0 = half*8;
  float a[8], h[8];
  bool afast = true;
  size_t hb = (((size_t)(b*2+i)*NC + c)*DI + d)*NS + n0;
  #pragma unroll
  for (int n=0;n<8;++n){
    a[n] = -__expf(A_log[((size_t)(i*DI)+d)*NS + n0+n]);
    float tgt = (float)(n0+n+1);
    afast = afast && (fabsf(a[n] + tgt) <= 1e-4f*tgt);
    h[n] = h0[hb+n];
  }
  const float Dd = Dp[i*DI + d];
  const size_t rb = ((size_t)(b*2+i)*Lx + (size_t)c*CT);
  for (int s=0; s<CT/SS; ++s){
    __syncthreads();
    #pragma unroll
    for (int it=0, e=tid; it<(SS*DI)/256; ++it, e+=256){
      int t = e >> 7, dd = e & (DI-1);
      size_t g = (rb + s*SS + t)*DI + dd;
      s_dt[t][dd] = dtg[g];
      s_x[t][dd]  = xcg[g];
      s_z[t][dd]  = zg[g];
    }
    {
      int t = tid >> 4, nn = tid & (NS-1);
      s_B[t][nn] = Bg[(rb + s*SS + t)*NS + nn];
      s_C[t][nn] = Cg[(rb + s*SS + t)*NS + nn];
    }
    __syncthreads();
    #pragma unroll
    for (int t=0;t<SS;++t){
      float dtt = s_dt[t][d];
      float xcv = s_x[t][d];
      float u = dtt * xcv;
      float4 b0 = *(const float4*)(&s_B[t][n0]);
      float4 b1 = *(const float4*)(&s_B[t][n0+4]);
      float4 c0 = *(const float4*)(&s_C[t][n0]);
      float4 c1 = *(const float4*)(&s_C[t][n0+4]);
      float bb[8] = {b0.x,b0.y,b0.z,b0.w,b1.x,b1.y,b1.z,b1.w};
      float cc[8] = {c0.x,c0.y,c0.z,c0.w,c1.x,c1.y,c1.z,c1.w};
      float part = 0.f;
      if (afast){
        float rr = __expf(-dtt);
        float dA;
        if (half){ float r2=rr*rr, r4=r2*r2; dA = r4*r4*rr; } else dA = rr;
        h[0] = fmaf(dA, h[0], u*bb[0]);
        part = fmaf(h[0], cc[0], part);
        #pragma unroll
        for (int n=1;n<8;++n){
          dA *= rr;
          h[n] = fmaf(dA, h[n], u*bb[n]);
          part = fmaf(h[n], cc[n], part);
        }
      } else {
        #pragma unroll
        for (int n=0;n<8;++n){
          float dA = __expf(a[n]*dtt);
          h[n] = fmaf(dA, h[n], u*bb[n]);
          part = fmaf(h[n], cc[n], part);
        }
      }
      float y = part + __shfl_xor(part, 1);
      if (half == 0){
        float zz = s_z[t][d];
        yout[(rb + s*SS + t)*DI + d] = fmaf(xcv, Dd, y) * (zz * fsig(zz));
      }
    }
  }
}

// ---------------------------------------------------------------------------
// KE: out-proj, sum both directions (dir1 read flipped)
// ---------------------------------------------------------------------------
__global__ __launch_bounds__(256) void ke_out(
    const float* __restrict__ yg, const float* __restrict__ ow, float* __restrict__ out)
{
  __shared__ float s_y0[TRE][DI];
  __shared__ float s_y1[TRE][DI];
  const int tid = threadIdx.x;
  const int bx = blockIdx.x;
  const int ntile = Lx / TRE;
  const int tile = bx % ntile; const int b = bx / ntile;
  const int l0 = tile * TRE;
  #pragma unroll
  for (int it=0, e=tid; it<(TRE*DI)/256; ++it, e+=256){
    int r = e >> 7, dd = e & (DI-1);
    s_y0[r][dd] = yg[((size_t)(b*2+0)*Lx + (size_t)(l0+r))*DI + dd];
    s_y1[r][dd] = yg[((size_t)(b*2+1)*Lx + (size_t)(Lx-1-(l0+r)))*DI + dd];
  }
  __syncthreads();
  const int m = tid & 63, r0 = tid >> 6;
  const float4* w0 = (const float4*)(ow + (size_t)m*DI);
  const float4* w1 = (const float4*)(ow + (size_t)(DM+m)*DI);
  float acc[4] = {0.f,0.f,0.f,0.f};
  #pragma unroll
  for (int k=0;k<DI/4;++k){
    float4 a0 = w0[k], a1 = w1[k];
    #pragma unroll
    for (int j=0;j<4;++j){
      const float4 y0 = *(const float4*)(&s_y0[r0+j*4][k*4]);
      const float4 y1 = *(const float4*)(&s_y1[r0+j*4][k*4]);
      acc[j] += dot4(a0,y0) + dot4(a1,y1);
    }
  }
  #pragma unroll
  for (int j=0;j<4;++j)
    out[((size_t)b*Lx + (size_t)(l0 + r0 + j*4))*DM + m] = acc[j];
}

extern "C" void kernel_launch(void* const* d_in, const int* in_sizes, int n_in,
                              void* d_out, int out_size, void* d_ws, size_t ws_size,
                              hipStream_t stream)
{
  const float* x      = (const float*)d_in[0];
  const float* ln_g   = (const float*)d_in[1];
  const float* ln_b   = (const float*)d_in[2];
  const float* in_w   = (const float*)d_in[3];
  const float* conv_w = (const float*)d_in[4];
  const float* conv_b = (const float*)d_in[5];
  const float* xp_w   = (const float*)d_in[6];
  const float* dtp_w  = (const float*)d_in[7];
  const float* dt_b   = (const float*)d_in[8];
  const float* A_log  = (const float*)d_in[9];
  const float* Dp     = (const float*)d_in[10];
  const float* ow     = (const float*)d_in[11];
  float* out = (float*)d_out;
  float* ws = (float*)d_ws;
  const size_t NBD = (size_t)Bsz*2*Lx*DI;     // 8,388,608
  const size_t NBN = (size_t)Bsz*2*Lx*NS;     // 1,048,576
  float* xcg = ws;
  float* dtg = xcg + NBD;
  float* zg  = dtg + NBD;
  float* Bg  = zg + NBD;
  float* Cg  = Bg + NBN;
  float* Pm  = Cg + NBN;          // Bsz*2*NC*DI*NS = 2,097,152 floats; becomes h0 after kc
  float* he  = out;               // hend staged in d_out (fully overwritten by ke)

  a1_front<<<dim3(Bsz*2*(Lx/64)), dim3(512), 0, stream>>>(
      x, ln_g, ln_b, in_w, conv_w, conv_b, xp_w, dtp_w, dt_b, xcg, dtg, zg, Bg, Cg);
  kb_pass1<<<dim3(Bsz*2*NC), dim3(256), 0, stream>>>(dtg, xcg, Bg, A_log, Pm, he);
  kc_pass2<<<dim3(Bsz*2), dim3(256), 0, stream>>>(Pm, he);
  kd_pass3<<<dim3(Bsz*2*NC), dim3(256), 0, stream>>>(dtg, xcg, Bg, Cg, A_log, Dp, Pm, zg, dtg);
  ke_out<<<dim3(Bsz*(Lx/TRE)), dim3(256), 0, stream>>>(dtg, ow, out);
}

// Round 7
// 233.267 us; speedup vs baseline: 1.9331x; 1.1650x over previous
//
#include <hip/hip_runtime.h>

#define Bsz 8
#define Lx 4096
#define DM 64
#define DI 128
#define NS 16
#define RK 4
#define KC 4
#define NC 64
#define CT 64
#define SS 16
#define TRE 16

typedef __attribute__((ext_vector_type(8))) __bf16 bf16x8v;
typedef __attribute__((ext_vector_type(4))) float f32x4;

__device__ __forceinline__ float fsig(float x){ return 1.f/(1.f+__expf(-x)); }
__device__ __forceinline__ float dot4(float4 a, float4 b){
  return fmaf(a.x,b.x, fmaf(a.y,b.y, fmaf(a.z,b.z, a.w*b.w)));
}

// ---------------------------------------------------------------------------
// A1 v6: LN + in_proj via bf16 MFMA (16x16x32) + conv + silu + x_proj + dt
// X staged bf16 [80][64] swz in uA; W staged bf16 [256][64] swz in uB.
// 8 waves: wave w owns N-tiles {2w,2w+1} (ch 32w..32w+31), all 5 M-tiles, K=2.
// After MFMA: xi -> uB fp32 [67][129], z -> uA [64][132]; rest identical to v5.
// ---------------------------------------------------------------------------
__global__ __launch_bounds__(512) void a1_front(
    const float* __restrict__ x, const float* __restrict__ ln_g, const float* __restrict__ ln_b,
    const float* __restrict__ in_w, const float* __restrict__ conv_w, const float* __restrict__ conv_b,
    const float* __restrict__ xp_w, const float* __restrict__ dtp_w, const float* __restrict__ dt_b,
    float* __restrict__ xcg, float* __restrict__ dtg, float* __restrict__ zg,
    float* __restrict__ Bg, float* __restrict__ Cg)
{
  __shared__ float uA[8704];
  __shared__ float uB[8704];
  const int tid = threadIdx.x;
  const int bx = blockIdx.x;
  const int tile = bx & 63;
  const int i = (bx >> 6) & 1;
  const int b = bx >> 7;
  const int l0 = tile * 64;
  const size_t rbase = (size_t)(b*2+i)*Lx + l0;

  // ---- phase 1: LN -> bf16 X (uA, swizzled) ; stage W -> bf16 (uB, swizzled) ----
  {
    const int wv8 = tid >> 6, lane = tid & 63;
    const float gg = ln_g[lane], bb = ln_b[lane];
    for (int lr = wv8; lr < 80; lr += 8) {
      float v = 0.f;
      int l = l0 - 3 + lr;
      if (lr < 67 && l >= 0) {
        int pl = i ? (Lx-1-l) : l;
        v = x[((size_t)b*Lx + pl)*DM + lane];
        float s = v, s2 = v*v;
        #pragma unroll
        for (int off=32; off; off>>=1){ s += __shfl_xor(s,off); s2 += __shfl_xor(s2,off); }
        float mu = s * (1.f/DM);
        float rs = rsqrtf(s2*(1.f/DM) - mu*mu + 1e-5f);
        v = (v-mu)*rs*gg + bb;
      }
      *(__bf16*)((char*)uA + ((lr*128 + lane*2) ^ ((lr&7)<<4))) = (__bf16)v;
    }
    #pragma unroll
    for (int it=0; it<8; ++it) {
      int g = it*512 + tid;
      int c = g >> 4, q = g & 15;
      float4 w = *(const float4*)(in_w + ((size_t)(i*2*DI) + c)*DM + q*4);
      int base = c*128 + q*8;
      int swz = (c&7)<<4;
      *(__bf16*)((char*)uB + ((base  ) ^ swz)) = (__bf16)w.x;
      *(__bf16*)((char*)uB + ((base+2) ^ swz)) = (__bf16)w.y;
      *(__bf16*)((char*)uB + ((base+4) ^ swz)) = (__bf16)w.z;
      *(__bf16*)((char*)uB + ((base+6) ^ swz)) = (__bf16)w.w;
    }
  }
  __syncthreads();

  // ---- phase 2: in_proj via MFMA ----
  const int lane = tid & 63, wv = tid >> 6;
  f32x4 acc[5][2];
  {
    f32x4 z4 = {0.f, 0.f, 0.f, 0.f};
    #pragma unroll
    for (int mt=0; mt<5; ++mt){ acc[mt][0] = z4; acc[mt][1] = z4; }
    bf16x8v bfr[2][2];
    #pragma unroll
    for (int ntl=0; ntl<2; ++ntl)
      #pragma unroll
      for (int kt=0; kt<2; ++kt){
        int c = (wv*2+ntl)*16 + (lane&15);
        int byt = (c*128 + kt*64 + (lane>>4)*16) ^ ((c&7)<<4);
        bfr[ntl][kt] = *(const bf16x8v*)((const char*)uB + byt);
      }
    #pragma unroll
    for (int mt=0; mt<5; ++mt){
      bf16x8v afr[2];
      #pragma unroll
      for (int kt=0; kt<2; ++kt){
        int row = mt*16 + (lane&15);
        int byt = (row*128 + kt*64 + (lane>>4)*16) ^ ((row&7)<<4);
        afr[kt] = *(const bf16x8v*)((const char*)uA + byt);
      }
      #pragma unroll
      for (int ntl=0; ntl<2; ++ntl){
        acc[mt][ntl] = __builtin_amdgcn_mfma_f32_16x16x32_bf16(afr[0], bfr[ntl][0], acc[mt][ntl], 0,0,0);
        acc[mt][ntl] = __builtin_amdgcn_mfma_f32_16x16x32_bf16(afr[1], bfr[ntl][1], acc[mt][ntl], 0,0,0);
      }
    }
  }
  __syncthreads();

  // ---- phase 3: frag writeout — xi -> uB[67][129], z -> uA[64][132] ----
  if (wv < 4) {
    #pragma unroll
    for (int mt=0; mt<5; ++mt)
      #pragma unroll
      for (int ntl=0; ntl<2; ++ntl)
        #pragma unroll
        for (int r=0; r<4; ++r){
          int m = mt*16 + (lane>>4)*4 + r;
          if (m <= 66) uB[m*129 + (wv*2+ntl)*16 + (lane&15)] = acc[mt][ntl][r];
        }
  } else {
    #pragma unroll
    for (int mt=0; mt<5; ++mt)
      #pragma unroll
      for (int ntl=0; ntl<2; ++ntl)
        #pragma unroll
        for (int r=0; r<4; ++r){
          int m = mt*16 + (lane>>4)*4 + r;
          if (m >= 3 && m <= 66)
            uA[(m-3)*132 + ((wv-4)*2+ntl)*16 + (lane&15)] = acc[mt][ntl][r];
        }
  }
  __syncthreads();

  // ---- phase 3b: z -> global, coalesced ----
  #pragma unroll
  for (int it=0; it<4; ++it) {
    int f = it*512 + tid;
    int row = f >> 5, c0 = (f & 31) * 4;
    float4 v = *(const float4*)&uA[row*132 + c0];
    *(float4*)&zg[(rbase + row)*DI + c0] = v;
  }
  __syncthreads();

  // ---- phase 4: causal conv + silu -> s_xc (uA) + xcg ----
  {
    const int d = tid & 127, rh = tid >> 7;
    float4 cw = *(const float4*)(conv_w + (size_t)(i*DI + d)*KC);
    const float cb = conv_b[i*DI + d];
    #pragma unroll 4
    for (int rr=0; rr<16; ++rr) {
      int lr = 3 + rh*16 + rr;
      float v0 = uB[(lr-3)*129 + d];
      float v1 = uB[(lr-2)*129 + d];
      float v2 = uB[(lr-1)*129 + d];
      float v3 = uB[(lr  )*129 + d];
      float a = cb + cw.x*v0 + cw.y*v1 + cw.z*v2 + cw.w*v3;
      float xc = a * fsig(a);
      int r = lr - 3;
      uA[r*132 + d] = xc;
      xcg[(rbase + r)*DI + d] = xc;
    }
  }
  __syncthreads();

  // ---- phase 5: stage xp_w into uB (s_xi dead) ----
  for (int e = tid; e < 36*32; e += 512) {
    int j = e >> 5, q = e & 31;
    *(float4*)&uB[j*132 + 4*q] = *(const float4*)(xp_w + ((size_t)(i*36) + j)*DI + q*4);
  }
  __syncthreads();

  // ---- phase 6: x_proj, thread = (2 rows) x (3 outs strided by 16) ----
  {
    const int rg2 = tid & 31, jg = tid >> 5;
    const int j2 = (jg < 4) ? (jg + 32) : 35;
    float a2[2][3];
    #pragma unroll
    for (int rc=0;rc<2;++rc)
      #pragma unroll
      for (int jc=0;jc<3;++jc) a2[rc][jc]=0.f;
    #pragma unroll 4
    for (int q=0; q<32; ++q) {
      float4 x0 = *(const float4*)&uA[(rg2*2  )*132 + 4*q];
      float4 x1 = *(const float4*)&uA[(rg2*2+1)*132 + 4*q];
      float4 w0 = *(const float4*)&uB[jg*132 + 4*q];
      float4 w1 = *(const float4*)&uB[(jg+16)*132 + 4*q];
      float4 w2 = *(const float4*)&uB[j2*132 + 4*q];
      a2[0][0] += dot4(x0,w0); a2[0][1] += dot4(x0,w1); a2[0][2] += dot4(x0,w2);
      a2[1][0] += dot4(x1,w0); a2[1][1] += dot4(x1,w1); a2[1][2] += dot4(x1,w2);
    }
    #pragma unroll
    for (int rc=0;rc<2;++rc) {
      int r = rg2*2 + rc;
      if (jg < 4) uA[8448 + r*4 + jg] = a2[rc][0];
      else        uB[4864 + r*32 + (jg-4)] = a2[rc][0];
      uB[4864 + r*32 + (jg+12)] = a2[rc][1];
      if (jg < 4) uB[4864 + r*32 + (jg+28)] = a2[rc][2];
    }
  }
  __syncthreads();

  // ---- phase 6b: B/C -> global coalesced ----
  #pragma unroll
  for (int it=0; it<2; ++it) {
    int e = it*512 + tid;
    int r = e >> 4, n = e & 15;
    Bg[(rbase + r)*NS + n] = uB[4864 + r*32 + n];
    Cg[(rbase + r)*NS + n] = uB[4864 + r*32 + 16 + n];
  }

  // ---- phase 7: dt = softplus(dtl @ dtp_w^T + bias) ----
  #pragma unroll 4
  for (int it=0; it<16; ++it) {
    int e = it*512 + tid;
    int r = e >> 7, d = e & 127;
    float4 dl = *(const float4*)&uA[8448 + r*4];
    float4 w  = *(const float4*)(dtp_w + (size_t)(i*DI + d)*RK);
    float a = dt_b[i*DI + d] + dot4(w, dl);
    dtg[(rbase + r)*DI + d] = (a > 20.f) ? a : log1pf(__expf(a));
  }
}

// ---------------------------------------------------------------------------
// KB: pass1 — per-chunk local scan (h0=0) + P = exp(A*sum(dt))
// ---------------------------------------------------------------------------
__global__ __launch_bounds__(256) void kb_pass1(
    const float* __restrict__ dtg, const float* __restrict__ xcg, const float* __restrict__ Bg,
    const float* __restrict__ A_log,
    float* __restrict__ Pm, float* __restrict__ hend)
{
  __shared__ float s_dt[SS][DI];
  __shared__ float s_x[SS][DI];
  __shared__ float s_B[SS][NS];
  const int tid = threadIdx.x;
  const int bx = blockIdx.x;
  const int c = bx % NC; const int i = (bx/NC)&1; const int b = bx/(2*NC);
  const int d = tid >> 1, half = tid & 1, n0 = half*8;
  float a[8], h[8];
  bool afast = true;
  #pragma unroll
  for (int n=0;n<8;++n){
    a[n] = -__expf(A_log[((size_t)(i*DI)+d)*NS + n0+n]);
    float tgt = (float)(n0+n+1);
    afast = afast && (fabsf(a[n] + tgt) <= 1e-4f*tgt);
    h[n] = 0.f;
  }
  float S = 0.f;
  const size_t rb = ((size_t)(b*2+i)*Lx + (size_t)c*CT);
  for (int s=0; s<CT/SS; ++s){
    __syncthreads();
    #pragma unroll
    for (int it=0, e=tid; it<(SS*DI)/256; ++it, e+=256){
      int t = e >> 7, dd = e & (DI-1);
      size_t g = (rb + s*SS + t)*DI + dd;
      s_dt[t][dd] = dtg[g];
      s_x[t][dd]  = xcg[g];
    }
    {
      int t = tid >> 4, nn = tid & (NS-1);
      s_B[t][nn] = Bg[(rb + s*SS + t)*NS + nn];
    }
    __syncthreads();
    #pragma unroll
    for (int t=0;t<SS;++t){
      float dtt = s_dt[t][d];
      float u = dtt * s_x[t][d];
      S += dtt;
      float4 b0 = *(const float4*)(&s_B[t][n0]);
      float4 b1 = *(const float4*)(&s_B[t][n0+4]);
      float bb[8] = {b0.x,b0.y,b0.z,b0.w,b1.x,b1.y,b1.z,b1.w};
      if (afast){
        float rr = __expf(-dtt);
        float dA;
        if (half){ float r2=rr*rr, r4=r2*r2; dA = r4*r4*rr; } else dA = rr;
        h[0] = fmaf(dA, h[0], u*bb[0]);
        #pragma unroll
        for (int n=1;n<8;++n){ dA *= rr; h[n] = fmaf(dA, h[n], u*bb[n]); }
      } else {
        #pragma unroll
        for (int n=0;n<8;++n){
          float dA = __expf(a[n]*dtt);
          h[n] = fmaf(dA, h[n], u*bb[n]);
        }
      }
    }
  }
  size_t ob = (((size_t)(b*2+i)*NC + c)*DI + d)*NS + n0;
  #pragma unroll
  for (int n=0;n<8;++n){
    Pm[ob+n] = __expf(a[n]*S);
    hend[ob+n] = h[n];
  }
}

// ---------------------------------------------------------------------------
// KC: pass2 — propagate chunk boundary states; h0 written IN PLACE over Pm
// ---------------------------------------------------------------------------
__global__ __launch_bounds__(256) void kc_pass2(
    float* __restrict__ Pm, const float* __restrict__ hend)
{
  const int tid = threadIdx.x;
  const int bi = blockIdx.x;
  const int d = tid>>1, n0 = (tid&1)*8;
  float h[8];
  #pragma unroll
  for (int n=0;n<8;++n) h[n]=0.f;
  for (int c=0;c<NC;++c){
    size_t ob = (((size_t)bi*NC + c)*DI + d)*NS + n0;
    float p[8], he[8];
    #pragma unroll
    for (int n=0;n<8;++n){ p[n]=Pm[ob+n]; he[n]=hend[ob+n]; }
    #pragma unroll
    for (int n=0;n<8;++n){ Pm[ob+n] = h[n]; h[n] = fmaf(p[n], h[n], he[n]); }
  }
}

// ---------------------------------------------------------------------------
// KD: pass3 — scan with true h0, y = C.h + D-skip, gate silu(z); y -> dtg
// ---------------------------------------------------------------------------
__global__ __launch_bounds__(256) void kd_pass3(
    const float* dtg, const float* __restrict__ xcg, const float* __restrict__ Bg,
    const float* __restrict__ Cg, const float* __restrict__ A_log, const float* __restrict__ Dp,
    const float* __restrict__ h0, const float* __restrict__ zg, float* yout)
{
  __shared__ float s_dt[SS][DI];
  __shared__ float s_x[SS][DI];
  __shared__ float s_z[SS][DI];
  __shared__ float s_B[SS][NS];
  __shared__ float s_C[SS][NS];
  const int tid = threadIdx.x;
  const int bx = blockIdx.x;
  const int c = bx % NC; const int i = (bx/NC)&1; const int b = bx/(2*NC);
  const int d = tid >> 1, half = tid & 1, n0 = half*8;
  float a[8], h[8];
  bool afast = true;
  size_t hb = (((size_t)(b*2+i)*NC + c)*DI + d)*NS + n0;
  #pragma unroll
  for (int n=0;n<8;++n){
    a[n] = -__expf(A_log[((size_t)(i*DI)+d)*NS + n0+n]);
    float tgt = (float)(n0+n+1);
    afast = afast && (fabsf(a[n] + tgt) <= 1e-4f*tgt);
    h[n] = h0[hb+n];
  }
  const float Dd = Dp[i*DI + d];
  const size_t rb = ((size_t)(b*2+i)*Lx + (size_t)c*CT);
  for (int s=0; s<CT/SS; ++s){
    __syncthreads();
    #pragma unroll
    for (int it=0, e=tid; it<(SS*DI)/256; ++it, e+=256){
      int t = e >> 7, dd = e & (DI-1);
      size_t g = (rb + s*SS + t)*DI + dd;
      s_dt[t][dd] = dtg[g];
      s_x[t][dd]  = xcg[g];
      s_z[t][dd]  = zg[g];
    }
    {
      int t = tid >> 4, nn = tid & (NS-1);
      s_B[t][nn] = Bg[(rb + s*SS + t)*NS + nn];
      s_C[t][nn] = Cg[(rb + s*SS + t)*NS + nn];
    }
    __syncthreads();
    #pragma unroll
    for (int t=0;t<SS;++t){
      float dtt = s_dt[t][d];
      float xcv = s_x[t][d];
      float u = dtt * xcv;
      float4 b0 = *(const float4*)(&s_B[t][n0]);
      float4 b1 = *(const float4*)(&s_B[t][n0+4]);
      float4 c0 = *(const float4*)(&s_C[t][n0]);
      float4 c1 = *(const float4*)(&s_C[t][n0+4]);
      float bb[8] = {b0.x,b0.y,b0.z,b0.w,b1.x,b1.y,b1.z,b1.w};
      float cc[8] = {c0.x,c0.y,c0.z,c0.w,c1.x,c1.y,c1.z,c1.w};
      float part = 0.f;
      if (afast){
        float rr = __expf(-dtt);
        float dA;
        if (half){ float r2=rr*rr, r4=r2*r2; dA = r4*r4*rr; } else dA = rr;
        h[0] = fmaf(dA, h[0], u*bb[0]);
        part = fmaf(h[0], cc[0], part);
        #pragma unroll
        for (int n=1;n<8;++n){
          dA *= rr;
          h[n] = fmaf(dA, h[n], u*bb[n]);
          part = fmaf(h[n], cc[n], part);
        }
      } else {
        #pragma unroll
        for (int n=0;n<8;++n){
          float dA = __expf(a[n]*dtt);
          h[n] = fmaf(dA, h[n], u*bb[n]);
          part = fmaf(h[n], cc[n], part);
        }
      }
      float y = part + __shfl_xor(part, 1);
      if (half == 0){
        float zz = s_z[t][d];
        yout[(rb + s*SS + t)*DI + d] = fmaf(xcv, Dd, y) * (zz * fsig(zz));
      }
    }
  }
}

// ---------------------------------------------------------------------------
// KE: out-proj, sum both directions (dir1 read flipped)
// ---------------------------------------------------------------------------
__global__ __launch_bounds__(256) void ke_out(
    const float* __restrict__ yg, const float* __restrict__ ow, float* __restrict__ out)
{
  __shared__ float s_y0[TRE][DI];
  __shared__ float s_y1[TRE][DI];
  const int tid = threadIdx.x;
  const int bx = blockIdx.x;
  const int ntile = Lx / TRE;
  const int tile = bx % ntile; const int b = bx / ntile;
  const int l0 = tile * TRE;
  #pragma unroll
  for (int it=0, e=tid; it<(TRE*DI)/256; ++it, e+=256){
    int r = e >> 7, dd = e & (DI-1);
    s_y0[r][dd] = yg[((size_t)(b*2+0)*Lx + (size_t)(l0+r))*DI + dd];
    s_y1[r][dd] = yg[((size_t)(b*2+1)*Lx + (size_t)(Lx-1-(l0+r)))*DI + dd];
  }
  __syncthreads();
  const int m = tid & 63, r0 = tid >> 6;
  const float4* w0 = (const float4*)(ow + (size_t)m*DI);
  const float4* w1 = (const float4*)(ow + (size_t)(DM+m)*DI);
  float acc[4] = {0.f,0.f,0.f,0.f};
  #pragma unroll
  for (int k=0;k<DI/4;++k){
    float4 a0 = w0[k], a1 = w1[k];
    #pragma unroll
    for (int j=0;j<4;++j){
      const float4 y0 = *(const float4*)(&s_y0[r0+j*4][k*4]);
      const float4 y1 = *(const float4*)(&s_y1[r0+j*4][k*4]);
      acc[j] += dot4(a0,y0) + dot4(a1,y1);
    }
  }
  #pragma unroll
  for (int j=0;j<4;++j)
    out[((size_t)b*Lx + (size_t)(l0 + r0 + j*4))*DM + m] = acc[j];
}

extern "C" void kernel_launch(void* const* d_in, const int* in_sizes, int n_in,
                              void* d_out, int out_size, void* d_ws, size_t ws_size,
                              hipStream_t stream)
{
  const float* x      = (const float*)d_in[0];
  const float* ln_g   = (const float*)d_in[1];
  const float* ln_b   = (const float*)d_in[2];
  const float* in_w   = (const float*)d_in[3];
  const float* conv_w = (const float*)d_in[4];
  const float* conv_b = (const float*)d_in[5];
  const float* xp_w   = (const float*)d_in[6];
  const float* dtp_w  = (const float*)d_in[7];
  const float* dt_b   = (const float*)d_in[8];
  const float* A_log  = (const float*)d_in[9];
  const float* Dp     = (const float*)d_in[10];
  const float* ow     = (const float*)d_in[11];
  float* out = (float*)d_out;
  float* ws = (float*)d_ws;
  const size_t NBD = (size_t)Bsz*2*Lx*DI;     // 8,388,608
  const size_t NBN = (size_t)Bsz*2*Lx*NS;     // 1,048,576
  float* xcg = ws;
  float* dtg = xcg + NBD;
  float* zg  = dtg + NBD;
  float* Bg  = zg + NBD;
  float* Cg  = Bg + NBN;
  float* Pm  = Cg + NBN;          // Bsz*2*NC*DI*NS = 2,097,152 floats; becomes h0 after kc
  float* he  = out;               // hend staged in d_out (fully overwritten by ke)

  a1_front<<<dim3(Bsz*2*(Lx/64)), dim3(512), 0, stream>>>(
      x, ln_g, ln_b, in_w, conv_w, conv_b, xp_w, dtp_w, dt_b, xcg, dtg, zg, Bg, Cg);
  kb_pass1<<<dim3(Bsz*2*NC), dim3(256), 0, stream>>>(dtg, xcg, Bg, A_log, Pm, he);
  kc_pass2<<<dim3(Bsz*2), dim3(256), 0, stream>>>(Pm, he);
  kd_pass3<<<dim3(Bsz*2*NC), dim3(256), 0, stream>>>(dtg, xcg, Bg, Cg, A_log, Dp, Pm, zg, dtg);
  ke_out<<<dim3(Bsz*(Lx/TRE)), dim3(256), 0, stream>>>(dtg, ow, out);
}